// Round 16
// baseline (47.020 us; speedup 1.0000x reference)
//
#include <hip/hip_runtime.h>

// 3x3 majority, replicate pad, 8 bins, ties -> smallest, 8 fused iterations.
// Bit-sliced planes (3 bits/label). Lane = one FULL tile row of 64 px as a
// u64 (two u32 words). TWO vertically-stacked 64x32 tiles per wave:
// lanes 0..31 = tile A rows (input rows 32*by-8+lane), lanes 32..63 = tile B
// rows (input rows 32*by+8+(lane-32) = 32*by+lane-24). Each tile outputs
// 48x16 (halo 8). DPP seam garbage (lane 31<->32, wave ends) lands in halo
// rows. Vertical: DPP wave_shr1/shl1 bound_ctrl=1. Horizontal: in-lane u64
// funnels. Argmax: bitwise tournament (strict >, first max = smallest).
// Image-edge replicate: lane 8 = image row 0 (by==0), lane 55 = image row
// 767 (by==23); col patches on bx-edge. Waves 2048 -> 3072 (768 blocks,
// 3/CU): attacks the residency bottleneck identified in R10-R14.
// R16 = R15 with the tile-B row-map sign FIXED: gyu = by*32-8+lane-16 for
// lanes>=32 (R15 had +16 -> stores at rows up to 784 -> OOB crash).

static constexpr int IMG = 768;
static constexpr int NBX = 16;   // x-tiles (48 out cols each)
static constexpr int NBY = 24;   // y pairs (32 out rows each: A=16, B=16)

__device__ __forceinline__ unsigned bfi(unsigned m, unsigned a, unsigned b) {
  return (a & m) | (b & ~m);     // v_bfi_b32
}
__device__ __forceinline__ unsigned dppUp(unsigned x) {   // lane i <- lane i-1
  return (unsigned)__builtin_amdgcn_update_dpp(0, (int)x, 0x138, 0xF, 0xF, true);
}
__device__ __forceinline__ unsigned dppDn(unsigned x) {   // lane i <- lane i+1
  return (unsigned)__builtin_amdgcn_update_dpp(0, (int)x, 0x130, 0xF, 0xF, true);
}
__device__ __forceinline__ unsigned alignb(unsigned hi, unsigned lo, int s) {
  return __builtin_amdgcn_alignbit(hi, lo, s);   // ((hi:lo) >> s) low 32
}

struct C4 { unsigned b0, b1, b2, b3; };

__device__ __forceinline__ unsigned gt4(const C4& x, const C4& y) {  // x > y
  unsigned d = x.b0 ^ y.b0;
  unsigned g = d & x.b0;
  d = x.b1 ^ y.b1; g = bfi(d, d & x.b1, g);
  d = x.b2 ^ y.b2; g = bfi(d, d & x.b2, g);
  d = x.b3 ^ y.b3; g = bfi(d, d & x.b3, g);
  return g;
}
__device__ __forceinline__ C4 sel4(unsigned G, const C4& x, const C4& y) {
  C4 r; r.b0 = bfi(G, x.b0, y.b0); r.b1 = bfi(G, x.b1, y.b1);
  r.b2 = bfi(G, x.b2, y.b2); r.b3 = bfi(G, x.b3, y.b3); return r;
}
__device__ __forceinline__ void tourn8(const C4 c[8],
                                       unsigned& o0, unsigned& o1, unsigned& o2) {
  unsigned g01 = gt4(c[1], c[0]); C4 w01 = sel4(g01, c[1], c[0]);
  unsigned g23 = gt4(c[3], c[2]); C4 w23 = sel4(g23, c[3], c[2]);
  unsigned gA  = gt4(w23, w01);   C4 wA  = sel4(gA, w23, w01);
  unsigned iA0 = bfi(gA, g23, g01), iA1 = gA;
  unsigned g45 = gt4(c[5], c[4]); C4 w45 = sel4(g45, c[5], c[4]);
  unsigned g67 = gt4(c[7], c[6]); C4 w67 = sel4(g67, c[7], c[6]);
  unsigned gB  = gt4(w67, w45);   C4 wB  = sel4(gB, w67, w45);
  unsigned iB0 = bfi(gB, g67, g45), iB1 = gB;
  unsigned gR  = gt4(wB, wA);
  o0 = bfi(gR, iB0, iA0); o1 = bfi(gR, iB1, iA1); o2 = gR;
}

__global__ __launch_bounds__(256, 2) void fused_dpp2(
    const float* __restrict__ in, float* __restrict__ out) {
  const int wv = threadIdx.x >> 6;
  const int lane = threadIdx.x & 63;
  const int bx = blockIdx.x * 4 + wv;          // 0..15
  const int by = blockIdx.y, bz = blockIdx.z;

  const float* img = in + (size_t)bz * IMG * IMG;
  // lanes 0..31: tile A (gyu = 32*by - 8 + lane)
  // lanes 32..63: tile B (gyu = 32*by + lane - 24)
  const int gyu = by * 32 - 8 + lane - ((lane >= 32) ? 16 : 0);

  // ---- stage: one clamped 64-px row -> 6 plane words (branch-free)
  unsigned p0l = 0, p1l = 0, p2l = 0, p0h = 0, p1h = 0, p2h = 0;
  {
    int gy = gyu < 0 ? 0 : (gyu > IMG - 1 ? IMG - 1 : gyu);
    const float* rp = img + (size_t)gy * IMG;
    const int gx0 = bx * 48 - 8;
    const int gxc = gx0 < 0 ? 0 : (gx0 > IMG - 64 ? IMG - 64 : gx0);
#pragma unroll
    for (int g = 0; g < 8; ++g) {
      float4 f = *reinterpret_cast<const float4*>(rp + gxc + 4 * g);
      unsigned u0 = (unsigned)(int)f.x, u1 = (unsigned)(int)f.y;
      unsigned u2 = (unsigned)(int)f.z, u3 = (unsigned)(int)f.w;
      p0l |= ((u0 & 1u) | ((u1 & 1u) << 1) | ((u2 & 1u) << 2) | ((u3 & 1u) << 3)) << (4 * g);
      p1l |= (((u0 >> 1) & 1u) | (((u1 >> 1) & 1u) << 1) | (((u2 >> 1) & 1u) << 2) | (((u3 >> 1) & 1u) << 3)) << (4 * g);
      p2l |= (((u0 >> 2) & 1u) | (((u1 >> 2) & 1u) << 1) | (((u2 >> 2) & 1u) << 2) | (((u3 >> 2) & 1u) << 3)) << (4 * g);
    }
#pragma unroll
    for (int g = 0; g < 8; ++g) {
      float4 f = *reinterpret_cast<const float4*>(rp + gxc + 32 + 4 * g);
      unsigned u0 = (unsigned)(int)f.x, u1 = (unsigned)(int)f.y;
      unsigned u2 = (unsigned)(int)f.z, u3 = (unsigned)(int)f.w;
      p0h |= ((u0 & 1u) | ((u1 & 1u) << 1) | ((u2 & 1u) << 2) | ((u3 & 1u) << 3)) << (4 * g);
      p1h |= (((u0 >> 1) & 1u) | (((u1 >> 1) & 1u) << 1) | (((u2 >> 1) & 1u) << 2) | (((u3 >> 1) & 1u) << 3)) << (4 * g);
      p2h |= (((u0 >> 2) & 1u) | (((u1 >> 2) & 1u) << 1) | (((u2 >> 2) & 1u) << 2) | (((u3 >> 2) & 1u) << 3)) << (4 * g);
    }
    // realign loaded window (px gxc+i) to tile coords (px gx0+j)
    if (bx == 0) {            // desired = loaded << 8 bits (low 8 = halo garbage)
      p0h = alignb(p0h, p0l, 24); p0l <<= 8;
      p1h = alignb(p1h, p1l, 24); p1l <<= 8;
      p2h = alignb(p2h, p2l, 24); p2l <<= 8;
    } else if (bx == NBX - 1) {  // desired = loaded >> 8 bits (top 8 = garbage)
      p0l = alignb(p0h, p0l, 8); p0h >>= 8;
      p1l = alignb(p1h, p1l, 8); p1h >>= 8;
      p2l = alignb(p2h, p2l, 8); p2h >>= 8;
    }
  }

  const bool topE = (by == 0), botE = (by == NBY - 1);
  const bool lxE = (bx == 0), rxE = (bx == NBX - 1);
  const bool pTop = (lane == 8);    // gyu==0 only here when by==0
  const bool pBot = (lane == 55);   // gyu==767 only here when by==23

#pragma unroll 1
  for (int it = 0; it < 8; ++it) {
    // equality masks per word (15 ops each)
    unsigned e0[8], e1[8];
    {
      unsigned n0 = ~p0l, n1 = ~p1l, n2 = ~p2l;
      unsigned a00 = n1 & n0, a01 = n1 & p0l, a10 = p1l & n0, a11 = p1l & p0l;
      e0[0] = n2 & a00; e0[1] = n2 & a01; e0[2] = n2 & a10; e0[3] = n2 & a11;
      e0[4] = p2l & a00; e0[5] = p2l & a01; e0[6] = p2l & a10; e0[7] = p2l & a11;
    }
    {
      unsigned n0 = ~p0h, n1 = ~p1h, n2 = ~p2h;
      unsigned a00 = n1 & n0, a01 = n1 & p0h, a10 = p1h & n0, a11 = p1h & p0h;
      e1[0] = n2 & a00; e1[1] = n2 & a01; e1[2] = n2 & a10; e1[3] = n2 & a11;
      e1[4] = p2h & a00; e1[5] = p2h & a01; e1[6] = p2h & a10; e1[7] = p2h & a11;
    }

    // vertical 2-bit 3-count per bin per word; rows +-1 via DPP wave shifts
    // (lane 31<->32 seam and wave-end zeros land in the 8-row halos)
    unsigned VL0[8], VH0[8], VL1[8], VH1[8];
#pragma unroll
    for (int b = 0; b < 8; ++b) {
      unsigned eu = dppUp(e0[b]), ed = dppDn(e0[b]);
      if (topE) eu = pTop ? e0[b] : eu;
      if (botE) ed = pBot ? e0[b] : ed;
      unsigned t = eu ^ e0[b];
      VL0[b] = t ^ ed; VH0[b] = bfi(t, ed, e0[b]);   // majority(eu,e,ed)
      eu = dppUp(e1[b]); ed = dppDn(e1[b]);
      if (topE) eu = pTop ? e1[b] : eu;
      if (botE) ed = pBot ? e1[b] : ed;
      t = eu ^ e1[b];
      VL1[b] = t ^ ed; VH1[b] = bfi(t, ed, e1[b]);
    }

    // horizontal u64 funnel + 2b+2b+2b->4b adder -> per-bin 4-bit counts
    C4 c0[8], c1[8];
#pragma unroll
    for (int b = 0; b < 8; ++b) {
      unsigned AL0 = VL0[b] << 1,               AL1 = alignb(VL1[b], VL0[b], 31);
      unsigned AH0 = VH0[b] << 1,               AH1 = alignb(VH1[b], VH0[b], 31);
      unsigned CL0 = alignb(VL1[b], VL0[b], 1), CL1 = VL1[b] >> 1;
      unsigned CH0 = alignb(VH1[b], VH0[b], 1), CH1 = VH1[b] >> 1;
      if (lxE) { AL0 = bfi(0x100u, VL0[b], AL0); AH0 = bfi(0x100u, VH0[b], AH0); }
      if (rxE) { CL1 = bfi(0x00800000u, VL1[b], CL1); CH1 = bfi(0x00800000u, VH1[b], CH1); }

      // word0 adder: (A + V) + C -> c0[b]
      unsigned s0 = AL0 ^ VL0[b], cc = AL0 & VL0[b];
      unsigned u  = AH0 ^ VH0[b];
      unsigned s1 = u ^ cc, s2 = bfi(u, cc, VH0[b]);
      unsigned t0 = s0 ^ CL0, k0 = s0 & CL0, vv = s1 ^ CH0;
      c0[b].b0 = t0; c0[b].b1 = vv ^ k0;
      unsigned k1 = bfi(vv, k0, CH0);
      c0[b].b2 = s2 ^ k1; c0[b].b3 = s2 & k1;
      // word1 adder -> c1[b]
      s0 = AL1 ^ VL1[b]; cc = AL1 & VL1[b];
      u  = AH1 ^ VH1[b];
      s1 = u ^ cc; s2 = bfi(u, cc, VH1[b]);
      unsigned q0 = s0 ^ CL1; k0 = s0 & CL1; vv = s1 ^ CH1;
      c1[b].b0 = q0; c1[b].b1 = vv ^ k0;
      k1 = bfi(vv, k0, CH1);
      c1[b].b2 = s2 ^ k1; c1[b].b3 = s2 & k1;
    }

    // tournament argmax per word (depth 3; first max = smallest label)
    tourn8(c0, p0l, p1l, p2l);
    tourn8(c1, p0h, p1h, p2h);
  }

  // ---- store: valid lanes = rows 8..23 of each tile ((lane&31) in [8,24));
  // tile A -> rows 32*by+0..15, tile B -> rows 32*by+16..31 (gyu <= 767).
  // word0 bits 8..31 -> gx bx*48+0..23, word1 bits 0..23 -> bx*48+24..47.
  if ((lane & 31) >= 8 && (lane & 31) < 24) {
    float* orow = out + (size_t)bz * IMG * IMG + (size_t)gyu * IMG + bx * 48;
#pragma unroll
    for (int g = 0; g < 6; ++g) {
      const int j = 8 + 4 * g;
      float4 f;
      f.x = (float)(((p0l >> (j + 0)) & 1u) | (((p1l >> (j + 0)) & 1u) << 1) | (((p2l >> (j + 0)) & 1u) << 2));
      f.y = (float)(((p0l >> (j + 1)) & 1u) | (((p1l >> (j + 1)) & 1u) << 1) | (((p2l >> (j + 1)) & 1u) << 2));
      f.z = (float)(((p0l >> (j + 2)) & 1u) | (((p1l >> (j + 2)) & 1u) << 1) | (((p2l >> (j + 2)) & 1u) << 2));
      f.w = (float)(((p0l >> (j + 3)) & 1u) | (((p1l >> (j + 3)) & 1u) << 1) | (((p2l >> (j + 3)) & 1u) << 2));
      *reinterpret_cast<float4*>(orow + 4 * g) = f;
    }
#pragma unroll
    for (int g = 0; g < 6; ++g) {
      const int j = 4 * g;
      float4 f;
      f.x = (float)(((p0h >> (j + 0)) & 1u) | (((p1h >> (j + 0)) & 1u) << 1) | (((p2h >> (j + 0)) & 1u) << 2));
      f.y = (float)(((p0h >> (j + 1)) & 1u) | (((p1h >> (j + 1)) & 1u) << 1) | (((p2h >> (j + 1)) & 1u) << 2));
      f.z = (float)(((p0h >> (j + 2)) & 1u) | (((p1h >> (j + 2)) & 1u) << 1) | (((p2h >> (j + 2)) & 1u) << 2));
      f.w = (float)(((p0h >> (j + 3)) & 1u) | (((p1h >> (j + 3)) & 1u) << 1) | (((p2h >> (j + 3)) & 1u) << 2));
      *reinterpret_cast<float4*>(orow + 24 + 4 * g) = f;
    }
  }
}

extern "C" void kernel_launch(void* const* d_in, const int* in_sizes, int n_in,
                              void* d_out, int out_size, void* d_ws, size_t ws_size,
                              hipStream_t stream) {
  const float* clusters = (const float*)d_in[0];
  (void)in_sizes; (void)n_in; (void)out_size; (void)d_ws; (void)ws_size;

  // 4 wave-tile-pairs per 256-thread block; grid.x*4 = 16 x-tiles.
  dim3 grid(4, NBY, 8);   // 768 blocks = 3072 waves (3 blocks/CU)
  fused_dpp2<<<grid, 256, 0, stream>>>(clusters, (float*)d_out);
}

// Round 17
// 36.508 us; speedup vs baseline: 1.2879x; 1.2879x over previous
//
#include <hip/hip_runtime.h>

// 3x3 majority, replicate pad, 8 bins, ties -> smallest, 8 fused iterations.
// Bit-sliced planes (3 bits/label). Lane = one FULL tile row of 64 px as a
// u64 (two u32 words). Wave = 64x64 input tile -> 48x48 output (halo 8).
// Vertical: DPP wave_shr1/wave_shl1 bound_ctrl=1 (lanes 0/63 get 0 = halo).
// Horizontal: in-lane u64 funnel shifts. Argmax: bitwise tournament
// (depth 3, strict >, scan order => first max = smallest label).
// Staging: branch-free clamped 64-px load + funnel realign on bx-edges.
// Image-edge replicate: row patch at lane 8/55 on by-edge; col bfi patches.
// R17 = R14 + amdgpu_waves_per_eu(2,2): pin the scheduler's occupancy
// target to the grid's actual 2 waves/SIMD so it spends VGPRs on ILP
// (R10/R16 compiled to 44/56 VGPR -> bin chains serialized, ~1 inst/10cyc).

static constexpr int IMG = 768;
static constexpr int NBX = 16;   // 768/48 x-tiles
static constexpr int NBY = 16;   // 768/48 y-tiles

__device__ __forceinline__ unsigned bfi(unsigned m, unsigned a, unsigned b) {
  return (a & m) | (b & ~m);     // v_bfi_b32
}
__device__ __forceinline__ unsigned dppUp(unsigned x) {   // lane i <- lane i-1
  return (unsigned)__builtin_amdgcn_update_dpp(0, (int)x, 0x138, 0xF, 0xF, true);
}
__device__ __forceinline__ unsigned dppDn(unsigned x) {   // lane i <- lane i+1
  return (unsigned)__builtin_amdgcn_update_dpp(0, (int)x, 0x130, 0xF, 0xF, true);
}
__device__ __forceinline__ unsigned alignb(unsigned hi, unsigned lo, int s) {
  return __builtin_amdgcn_alignbit(hi, lo, s);   // ((hi:lo) >> s) low 32
}

struct C4 { unsigned b0, b1, b2, b3; };

__device__ __forceinline__ unsigned gt4(const C4& x, const C4& y) {  // x > y
  unsigned d = x.b0 ^ y.b0;
  unsigned g = d & x.b0;
  d = x.b1 ^ y.b1; g = bfi(d, d & x.b1, g);
  d = x.b2 ^ y.b2; g = bfi(d, d & x.b2, g);
  d = x.b3 ^ y.b3; g = bfi(d, d & x.b3, g);
  return g;
}
__device__ __forceinline__ C4 sel4(unsigned G, const C4& x, const C4& y) {
  C4 r; r.b0 = bfi(G, x.b0, y.b0); r.b1 = bfi(G, x.b1, y.b1);
  r.b2 = bfi(G, x.b2, y.b2); r.b3 = bfi(G, x.b3, y.b3); return r;
}
__device__ __forceinline__ void tourn8(const C4 c[8],
                                       unsigned& o0, unsigned& o1, unsigned& o2) {
  unsigned g01 = gt4(c[1], c[0]); C4 w01 = sel4(g01, c[1], c[0]);
  unsigned g23 = gt4(c[3], c[2]); C4 w23 = sel4(g23, c[3], c[2]);
  unsigned gA  = gt4(w23, w01);   C4 wA  = sel4(gA, w23, w01);
  unsigned iA0 = bfi(gA, g23, g01), iA1 = gA;
  unsigned g45 = gt4(c[5], c[4]); C4 w45 = sel4(g45, c[5], c[4]);
  unsigned g67 = gt4(c[7], c[6]); C4 w67 = sel4(g67, c[7], c[6]);
  unsigned gB  = gt4(w67, w45);   C4 wB  = sel4(gB, w67, w45);
  unsigned iB0 = bfi(gB, g67, g45), iB1 = gB;
  unsigned gR  = gt4(wB, wA);
  o0 = bfi(gR, iB0, iA0); o1 = bfi(gR, iB1, iA1); o2 = gR;
}

__global__ __attribute__((amdgpu_waves_per_eu(2, 2))) __launch_bounds__(256)
void fused_dpp(const float* __restrict__ in, float* __restrict__ out) {
  const int wv = threadIdx.x >> 6;
  const int lane = threadIdx.x & 63;
  const int bx = blockIdx.x * 4 + wv;          // 0..15
  const int by = blockIdx.y, bz = blockIdx.z;

  const float* img = in + (size_t)bz * IMG * IMG;
  const int gyu = by * 48 - 8 + lane;          // unclamped global row

  // ---- stage: one clamped 64-px row -> 6 plane words (branch-free)
  unsigned p0l = 0, p1l = 0, p2l = 0, p0h = 0, p1h = 0, p2h = 0;
  {
    int gy = gyu < 0 ? 0 : (gyu > IMG - 1 ? IMG - 1 : gyu);
    const float* rp = img + (size_t)gy * IMG;
    const int gx0 = bx * 48 - 8;
    const int gxc = gx0 < 0 ? 0 : (gx0 > IMG - 64 ? IMG - 64 : gx0);
#pragma unroll
    for (int g = 0; g < 8; ++g) {
      float4 f = *reinterpret_cast<const float4*>(rp + gxc + 4 * g);
      unsigned u0 = (unsigned)(int)f.x, u1 = (unsigned)(int)f.y;
      unsigned u2 = (unsigned)(int)f.z, u3 = (unsigned)(int)f.w;
      p0l |= ((u0 & 1u) | ((u1 & 1u) << 1) | ((u2 & 1u) << 2) | ((u3 & 1u) << 3)) << (4 * g);
      p1l |= (((u0 >> 1) & 1u) | (((u1 >> 1) & 1u) << 1) | (((u2 >> 1) & 1u) << 2) | (((u3 >> 1) & 1u) << 3)) << (4 * g);
      p2l |= (((u0 >> 2) & 1u) | (((u1 >> 2) & 1u) << 1) | (((u2 >> 2) & 1u) << 2) | (((u3 >> 2) & 1u) << 3)) << (4 * g);
    }
#pragma unroll
    for (int g = 0; g < 8; ++g) {
      float4 f = *reinterpret_cast<const float4*>(rp + gxc + 32 + 4 * g);
      unsigned u0 = (unsigned)(int)f.x, u1 = (unsigned)(int)f.y;
      unsigned u2 = (unsigned)(int)f.z, u3 = (unsigned)(int)f.w;
      p0h |= ((u0 & 1u) | ((u1 & 1u) << 1) | ((u2 & 1u) << 2) | ((u3 & 1u) << 3)) << (4 * g);
      p1h |= (((u0 >> 1) & 1u) | (((u1 >> 1) & 1u) << 1) | (((u2 >> 1) & 1u) << 2) | (((u3 >> 1) & 1u) << 3)) << (4 * g);
      p2h |= (((u0 >> 2) & 1u) | (((u1 >> 2) & 1u) << 1) | (((u2 >> 2) & 1u) << 2) | (((u3 >> 2) & 1u) << 3)) << (4 * g);
    }
    // realign loaded window (px gxc+i) to tile coords (px gx0+j)
    if (bx == 0) {            // desired = loaded << 8 bits (low 8 = halo garbage)
      p0h = alignb(p0h, p0l, 24); p0l <<= 8;
      p1h = alignb(p1h, p1l, 24); p1l <<= 8;
      p2h = alignb(p2h, p2l, 24); p2l <<= 8;
    } else if (bx == NBX - 1) {  // desired = loaded >> 8 bits (top 8 = garbage)
      p0l = alignb(p0h, p0l, 8); p0h >>= 8;
      p1l = alignb(p1h, p1l, 8); p1h >>= 8;
      p2l = alignb(p2h, p2l, 8); p2h >>= 8;
    }
  }

  const bool topE = (by == 0), botE = (by == NBY - 1);
  const bool lxE = (bx == 0), rxE = (bx == NBX - 1);
  const bool pTop = (lane == 8);    // image row 0 (gyu==0) when by==0
  const bool pBot = (lane == 55);   // image row 767 when by==15

#pragma unroll 1
  for (int it = 0; it < 8; ++it) {
    // equality masks per word (15 ops each)
    unsigned e0[8], e1[8];
    {
      unsigned n0 = ~p0l, n1 = ~p1l, n2 = ~p2l;
      unsigned a00 = n1 & n0, a01 = n1 & p0l, a10 = p1l & n0, a11 = p1l & p0l;
      e0[0] = n2 & a00; e0[1] = n2 & a01; e0[2] = n2 & a10; e0[3] = n2 & a11;
      e0[4] = p2l & a00; e0[5] = p2l & a01; e0[6] = p2l & a10; e0[7] = p2l & a11;
    }
    {
      unsigned n0 = ~p0h, n1 = ~p1h, n2 = ~p2h;
      unsigned a00 = n1 & n0, a01 = n1 & p0h, a10 = p1h & n0, a11 = p1h & p0h;
      e1[0] = n2 & a00; e1[1] = n2 & a01; e1[2] = n2 & a10; e1[3] = n2 & a11;
      e1[4] = p2h & a00; e1[5] = p2h & a01; e1[6] = p2h & a10; e1[7] = p2h & a11;
    }

    // vertical 2-bit 3-count per bin per word; rows +-1 via DPP wave shifts
    unsigned VL0[8], VH0[8], VL1[8], VH1[8];
#pragma unroll
    for (int b = 0; b < 8; ++b) {
      unsigned eu = dppUp(e0[b]), ed = dppDn(e0[b]);
      if (topE) eu = pTop ? e0[b] : eu;
      if (botE) ed = pBot ? e0[b] : ed;
      unsigned t = eu ^ e0[b];
      VL0[b] = t ^ ed; VH0[b] = bfi(t, ed, e0[b]);   // majority(eu,e,ed)
      eu = dppUp(e1[b]); ed = dppDn(e1[b]);
      if (topE) eu = pTop ? e1[b] : eu;
      if (botE) ed = pBot ? e1[b] : ed;
      t = eu ^ e1[b];
      VL1[b] = t ^ ed; VH1[b] = bfi(t, ed, e1[b]);
    }

    // horizontal u64 funnel + 2b+2b+2b->4b adder -> per-bin 4-bit counts
    C4 c0[8], c1[8];
#pragma unroll
    for (int b = 0; b < 8; ++b) {
      unsigned AL0 = VL0[b] << 1,               AL1 = alignb(VL1[b], VL0[b], 31);
      unsigned AH0 = VH0[b] << 1,               AH1 = alignb(VH1[b], VH0[b], 31);
      unsigned CL0 = alignb(VL1[b], VL0[b], 1), CL1 = VL1[b] >> 1;
      unsigned CH0 = alignb(VH1[b], VH0[b], 1), CH1 = VH1[b] >> 1;
      if (lxE) { AL0 = bfi(0x100u, VL0[b], AL0); AH0 = bfi(0x100u, VH0[b], AH0); }
      if (rxE) { CL1 = bfi(0x00800000u, VL1[b], CL1); CH1 = bfi(0x00800000u, VH1[b], CH1); }

      // word0 adder: (A + V) + C -> c0[b]
      unsigned s0 = AL0 ^ VL0[b], cc = AL0 & VL0[b];
      unsigned u  = AH0 ^ VH0[b];
      unsigned s1 = u ^ cc, s2 = bfi(u, cc, VH0[b]);
      unsigned t0 = s0 ^ CL0, k0 = s0 & CL0, vv = s1 ^ CH0;
      c0[b].b0 = t0; c0[b].b1 = vv ^ k0;
      unsigned k1 = bfi(vv, k0, CH0);
      c0[b].b2 = s2 ^ k1; c0[b].b3 = s2 & k1;
      // word1 adder -> c1[b]
      s0 = AL1 ^ VL1[b]; cc = AL1 & VL1[b];
      u  = AH1 ^ VH1[b];
      s1 = u ^ cc; s2 = bfi(u, cc, VH1[b]);
      unsigned q0 = s0 ^ CL1; k0 = s0 & CL1; vv = s1 ^ CH1;
      c1[b].b0 = q0; c1[b].b1 = vv ^ k0;
      k1 = bfi(vv, k0, CH1);
      c1[b].b2 = s2 ^ k1; c1[b].b3 = s2 & k1;
    }

    // tournament argmax per word (depth 3; first max = smallest label)
    tourn8(c0, p0l, p1l, p2l);
    tourn8(c1, p0h, p1h, p2h);
  }

  // ---- store: lanes 8..55 = output rows; word0 bits 8..31 -> gx bx*48+0..23,
  // word1 bits 0..23 -> gx bx*48+24..47.
  if (lane >= 8 && lane < 56) {
    float* orow = out + (size_t)bz * IMG * IMG + (size_t)gyu * IMG + bx * 48;
#pragma unroll
    for (int g = 0; g < 6; ++g) {
      const int j = 8 + 4 * g;
      float4 f;
      f.x = (float)(((p0l >> (j + 0)) & 1u) | (((p1l >> (j + 0)) & 1u) << 1) | (((p2l >> (j + 0)) & 1u) << 2));
      f.y = (float)(((p0l >> (j + 1)) & 1u) | (((p1l >> (j + 1)) & 1u) << 1) | (((p2l >> (j + 1)) & 1u) << 2));
      f.z = (float)(((p0l >> (j + 2)) & 1u) | (((p1l >> (j + 2)) & 1u) << 1) | (((p2l >> (j + 2)) & 1u) << 2));
      f.w = (float)(((p0l >> (j + 3)) & 1u) | (((p1l >> (j + 3)) & 1u) << 1) | (((p2l >> (j + 3)) & 1u) << 2));
      *reinterpret_cast<float4*>(orow + 4 * g) = f;
    }
#pragma unroll
    for (int g = 0; g < 6; ++g) {
      const int j = 4 * g;
      float4 f;
      f.x = (float)(((p0h >> (j + 0)) & 1u) | (((p1h >> (j + 0)) & 1u) << 1) | (((p2h >> (j + 0)) & 1u) << 2));
      f.y = (float)(((p0h >> (j + 1)) & 1u) | (((p1h >> (j + 1)) & 1u) << 1) | (((p2h >> (j + 1)) & 1u) << 2));
      f.z = (float)(((p0h >> (j + 2)) & 1u) | (((p1h >> (j + 2)) & 1u) << 1) | (((p2h >> (j + 2)) & 1u) << 2));
      f.w = (float)(((p0h >> (j + 3)) & 1u) | (((p1h >> (j + 3)) & 1u) << 1) | (((p2h >> (j + 3)) & 1u) << 2));
      *reinterpret_cast<float4*>(orow + 24 + 4 * g) = f;
    }
  }
}

extern "C" void kernel_launch(void* const* d_in, const int* in_sizes, int n_in,
                              void* d_out, int out_size, void* d_ws, size_t ws_size,
                              hipStream_t stream) {
  const float* clusters = (const float*)d_in[0];
  (void)in_sizes; (void)n_in; (void)out_size; (void)d_ws; (void)ws_size;

  // 4 independent wave-tiles per 256-thread block; grid.x*4 = 16 x-tiles.
  dim3 grid(4, NBY, 8);
  fused_dpp<<<grid, 256, 0, stream>>>(clusters, (float*)d_out);
}

// Round 18
// 32.769 us; speedup vs baseline: 1.4349x; 1.1141x over previous
//
#include <hip/hip_runtime.h>

// 3x3 majority, replicate pad, 8 bins, ties -> smallest, 8 fused iterations.
// Bit-sliced planes (3 bits/label). Lane = one FULL tile row of 64 px as a
// u64 (two u32 words). Wave = 64x64 input tile -> 48x48 output (halo 8).
// Vertical: DPP wave_shr1/wave_shl1 bound_ctrl=1 (lanes 0/63 get 0 = halo).
// Horizontal: in-lane u64 funnel shifts. Argmax: bitwise tournament
// (depth 3, strict >, scan order => first max = smallest label).
// R18 = R14 with bfi() forced to a real v_bfi_b32 via inline asm. The C
// pattern (a&m)|(b&~m) fails LLVM's BFI match when ~m is CSE'd multi-use
// (sel4 shares ~G across 4 selects; gt4 across 3 merges) -> each "bfi"
// lowered as and+and+or. ~148 bfi/iter x ~2 extra ops matches the observed
// ~2.5x dynamic-instruction bloat vs static count (R16 VALUBusy analysis).

static constexpr int IMG = 768;
static constexpr int NBX = 16;   // 768/48 x-tiles
static constexpr int NBY = 16;   // 768/48 y-tiles

__device__ __forceinline__ unsigned bfi(unsigned m, unsigned a, unsigned b) {
  unsigned r;
  asm("v_bfi_b32 %0, %1, %2, %3" : "=v"(r) : "v"(m), "v"(a), "v"(b));
  return r;   // (a & m) | (b & ~m)
}
__device__ __forceinline__ unsigned dppUp(unsigned x) {   // lane i <- lane i-1
  return (unsigned)__builtin_amdgcn_update_dpp(0, (int)x, 0x138, 0xF, 0xF, true);
}
__device__ __forceinline__ unsigned dppDn(unsigned x) {   // lane i <- lane i+1
  return (unsigned)__builtin_amdgcn_update_dpp(0, (int)x, 0x130, 0xF, 0xF, true);
}
__device__ __forceinline__ unsigned alignb(unsigned hi, unsigned lo, int s) {
  return __builtin_amdgcn_alignbit(hi, lo, s);   // ((hi:lo) >> s) low 32
}

struct C4 { unsigned b0, b1, b2, b3; };

__device__ __forceinline__ unsigned gt4(const C4& x, const C4& y) {  // x > y
  unsigned d = x.b0 ^ y.b0;
  unsigned g = d & x.b0;
  d = x.b1 ^ y.b1; g = bfi(d, d & x.b1, g);
  d = x.b2 ^ y.b2; g = bfi(d, d & x.b2, g);
  d = x.b3 ^ y.b3; g = bfi(d, d & x.b3, g);
  return g;
}
__device__ __forceinline__ C4 sel4(unsigned G, const C4& x, const C4& y) {
  C4 r; r.b0 = bfi(G, x.b0, y.b0); r.b1 = bfi(G, x.b1, y.b1);
  r.b2 = bfi(G, x.b2, y.b2); r.b3 = bfi(G, x.b3, y.b3); return r;
}
__device__ __forceinline__ void tourn8(const C4 c[8],
                                       unsigned& o0, unsigned& o1, unsigned& o2) {
  unsigned g01 = gt4(c[1], c[0]); C4 w01 = sel4(g01, c[1], c[0]);
  unsigned g23 = gt4(c[3], c[2]); C4 w23 = sel4(g23, c[3], c[2]);
  unsigned gA  = gt4(w23, w01);   C4 wA  = sel4(gA, w23, w01);
  unsigned iA0 = bfi(gA, g23, g01), iA1 = gA;
  unsigned g45 = gt4(c[5], c[4]); C4 w45 = sel4(g45, c[5], c[4]);
  unsigned g67 = gt4(c[7], c[6]); C4 w67 = sel4(g67, c[7], c[6]);
  unsigned gB  = gt4(w67, w45);   C4 wB  = sel4(gB, w67, w45);
  unsigned iB0 = bfi(gB, g67, g45), iB1 = gB;
  unsigned gR  = gt4(wB, wA);
  o0 = bfi(gR, iB0, iA0); o1 = bfi(gR, iB1, iA1); o2 = gR;
}

__global__ __launch_bounds__(256, 2) void fused_dpp(
    const float* __restrict__ in, float* __restrict__ out) {
  const int wv = threadIdx.x >> 6;
  const int lane = threadIdx.x & 63;
  const int bx = blockIdx.x * 4 + wv;          // 0..15
  const int by = blockIdx.y, bz = blockIdx.z;

  const float* img = in + (size_t)bz * IMG * IMG;
  const int gyu = by * 48 - 8 + lane;          // unclamped global row

  // ---- stage: one clamped 64-px row -> 6 plane words (branch-free)
  unsigned p0l = 0, p1l = 0, p2l = 0, p0h = 0, p1h = 0, p2h = 0;
  {
    int gy = gyu < 0 ? 0 : (gyu > IMG - 1 ? IMG - 1 : gyu);
    const float* rp = img + (size_t)gy * IMG;
    const int gx0 = bx * 48 - 8;
    const int gxc = gx0 < 0 ? 0 : (gx0 > IMG - 64 ? IMG - 64 : gx0);
#pragma unroll
    for (int g = 0; g < 8; ++g) {
      float4 f = *reinterpret_cast<const float4*>(rp + gxc + 4 * g);
      unsigned u0 = (unsigned)(int)f.x, u1 = (unsigned)(int)f.y;
      unsigned u2 = (unsigned)(int)f.z, u3 = (unsigned)(int)f.w;
      p0l |= ((u0 & 1u) | ((u1 & 1u) << 1) | ((u2 & 1u) << 2) | ((u3 & 1u) << 3)) << (4 * g);
      p1l |= (((u0 >> 1) & 1u) | (((u1 >> 1) & 1u) << 1) | (((u2 >> 1) & 1u) << 2) | (((u3 >> 1) & 1u) << 3)) << (4 * g);
      p2l |= (((u0 >> 2) & 1u) | (((u1 >> 2) & 1u) << 1) | (((u2 >> 2) & 1u) << 2) | (((u3 >> 2) & 1u) << 3)) << (4 * g);
    }
#pragma unroll
    for (int g = 0; g < 8; ++g) {
      float4 f = *reinterpret_cast<const float4*>(rp + gxc + 32 + 4 * g);
      unsigned u0 = (unsigned)(int)f.x, u1 = (unsigned)(int)f.y;
      unsigned u2 = (unsigned)(int)f.z, u3 = (unsigned)(int)f.w;
      p0h |= ((u0 & 1u) | ((u1 & 1u) << 1) | ((u2 & 1u) << 2) | ((u3 & 1u) << 3)) << (4 * g);
      p1h |= (((u0 >> 1) & 1u) | (((u1 >> 1) & 1u) << 1) | (((u2 >> 1) & 1u) << 2) | (((u3 >> 1) & 1u) << 3)) << (4 * g);
      p2h |= (((u0 >> 2) & 1u) | (((u1 >> 2) & 1u) << 1) | (((u2 >> 2) & 1u) << 2) | (((u3 >> 2) & 1u) << 3)) << (4 * g);
    }
    // realign loaded window (px gxc+i) to tile coords (px gx0+j)
    if (bx == 0) {            // desired = loaded << 8 bits (low 8 = halo garbage)
      p0h = alignb(p0h, p0l, 24); p0l <<= 8;
      p1h = alignb(p1h, p1l, 24); p1l <<= 8;
      p2h = alignb(p2h, p2l, 24); p2l <<= 8;
    } else if (bx == NBX - 1) {  // desired = loaded >> 8 bits (top 8 = garbage)
      p0l = alignb(p0h, p0l, 8); p0h >>= 8;
      p1l = alignb(p1h, p1l, 8); p1h >>= 8;
      p2l = alignb(p2h, p2l, 8); p2h >>= 8;
    }
  }

  const bool topE = (by == 0), botE = (by == NBY - 1);
  const bool lxE = (bx == 0), rxE = (bx == NBX - 1);
  const bool pTop = (lane == 8);    // image row 0 (gyu==0) when by==0
  const bool pBot = (lane == 55);   // image row 767 when by==15

#pragma unroll 1
  for (int it = 0; it < 8; ++it) {
    // equality masks per word (15 ops each)
    unsigned e0[8], e1[8];
    {
      unsigned n0 = ~p0l, n1 = ~p1l, n2 = ~p2l;
      unsigned a00 = n1 & n0, a01 = n1 & p0l, a10 = p1l & n0, a11 = p1l & p0l;
      e0[0] = n2 & a00; e0[1] = n2 & a01; e0[2] = n2 & a10; e0[3] = n2 & a11;
      e0[4] = p2l & a00; e0[5] = p2l & a01; e0[6] = p2l & a10; e0[7] = p2l & a11;
    }
    {
      unsigned n0 = ~p0h, n1 = ~p1h, n2 = ~p2h;
      unsigned a00 = n1 & n0, a01 = n1 & p0h, a10 = p1h & n0, a11 = p1h & p0h;
      e1[0] = n2 & a00; e1[1] = n2 & a01; e1[2] = n2 & a10; e1[3] = n2 & a11;
      e1[4] = p2h & a00; e1[5] = p2h & a01; e1[6] = p2h & a10; e1[7] = p2h & a11;
    }

    // vertical 2-bit 3-count per bin per word; rows +-1 via DPP wave shifts
    unsigned VL0[8], VH0[8], VL1[8], VH1[8];
#pragma unroll
    for (int b = 0; b < 8; ++b) {
      unsigned eu = dppUp(e0[b]), ed = dppDn(e0[b]);
      if (topE) eu = pTop ? e0[b] : eu;
      if (botE) ed = pBot ? e0[b] : ed;
      unsigned t = eu ^ e0[b];
      VL0[b] = t ^ ed; VH0[b] = bfi(t, ed, e0[b]);   // majority(eu,e,ed)
      eu = dppUp(e1[b]); ed = dppDn(e1[b]);
      if (topE) eu = pTop ? e1[b] : eu;
      if (botE) ed = pBot ? e1[b] : ed;
      t = eu ^ e1[b];
      VL1[b] = t ^ ed; VH1[b] = bfi(t, ed, e1[b]);
    }

    // horizontal u64 funnel + 2b+2b+2b->4b adder -> per-bin 4-bit counts
    C4 c0[8], c1[8];
#pragma unroll
    for (int b = 0; b < 8; ++b) {
      unsigned AL0 = VL0[b] << 1,               AL1 = alignb(VL1[b], VL0[b], 31);
      unsigned AH0 = VH0[b] << 1,               AH1 = alignb(VH1[b], VH0[b], 31);
      unsigned CL0 = alignb(VL1[b], VL0[b], 1), CL1 = VL1[b] >> 1;
      unsigned CH0 = alignb(VH1[b], VH0[b], 1), CH1 = VH1[b] >> 1;
      if (lxE) { AL0 = bfi(0x100u, VL0[b], AL0); AH0 = bfi(0x100u, VH0[b], AH0); }
      if (rxE) { CL1 = bfi(0x00800000u, VL1[b], CL1); CH1 = bfi(0x00800000u, VH1[b], CH1); }

      // word0 adder: (A + V) + C -> c0[b]
      unsigned s0 = AL0 ^ VL0[b], cc = AL0 & VL0[b];
      unsigned u  = AH0 ^ VH0[b];
      unsigned s1 = u ^ cc, s2 = bfi(u, cc, VH0[b]);
      unsigned t0 = s0 ^ CL0, k0 = s0 & CL0, vv = s1 ^ CH0;
      c0[b].b0 = t0; c0[b].b1 = vv ^ k0;
      unsigned k1 = bfi(vv, k0, CH0);
      c0[b].b2 = s2 ^ k1; c0[b].b3 = s2 & k1;
      // word1 adder -> c1[b]
      s0 = AL1 ^ VL1[b]; cc = AL1 & VL1[b];
      u  = AH1 ^ VH1[b];
      s1 = u ^ cc; s2 = bfi(u, cc, VH1[b]);
      unsigned q0 = s0 ^ CL1; k0 = s0 & CL1; vv = s1 ^ CH1;
      c1[b].b0 = q0; c1[b].b1 = vv ^ k0;
      k1 = bfi(vv, k0, CH1);
      c1[b].b2 = s2 ^ k1; c1[b].b3 = s2 & k1;
    }

    // tournament argmax per word (depth 3; first max = smallest label)
    tourn8(c0, p0l, p1l, p2l);
    tourn8(c1, p0h, p1h, p2h);
  }

  // ---- store: lanes 8..55 = output rows; word0 bits 8..31 -> gx bx*48+0..23,
  // word1 bits 0..23 -> gx bx*48+24..47.
  if (lane >= 8 && lane < 56) {
    float* orow = out + (size_t)bz * IMG * IMG + (size_t)gyu * IMG + bx * 48;
#pragma unroll
    for (int g = 0; g < 6; ++g) {
      const int j = 8 + 4 * g;
      float4 f;
      f.x = (float)(((p0l >> (j + 0)) & 1u) | (((p1l >> (j + 0)) & 1u) << 1) | (((p2l >> (j + 0)) & 1u) << 2));
      f.y = (float)(((p0l >> (j + 1)) & 1u) | (((p1l >> (j + 1)) & 1u) << 1) | (((p2l >> (j + 1)) & 1u) << 2));
      f.z = (float)(((p0l >> (j + 2)) & 1u) | (((p1l >> (j + 2)) & 1u) << 1) | (((p2l >> (j + 2)) & 1u) << 2));
      f.w = (float)(((p0l >> (j + 3)) & 1u) | (((p1l >> (j + 3)) & 1u) << 1) | (((p2l >> (j + 3)) & 1u) << 2));
      *reinterpret_cast<float4*>(orow + 4 * g) = f;
    }
#pragma unroll
    for (int g = 0; g < 6; ++g) {
      const int j = 4 * g;
      float4 f;
      f.x = (float)(((p0h >> (j + 0)) & 1u) | (((p1h >> (j + 0)) & 1u) << 1) | (((p2h >> (j + 0)) & 1u) << 2));
      f.y = (float)(((p0h >> (j + 1)) & 1u) | (((p1h >> (j + 1)) & 1u) << 1) | (((p2h >> (j + 1)) & 1u) << 2));
      f.z = (float)(((p0h >> (j + 2)) & 1u) | (((p1h >> (j + 2)) & 1u) << 1) | (((p2h >> (j + 2)) & 1u) << 2));
      f.w = (float)(((p0h >> (j + 3)) & 1u) | (((p1h >> (j + 3)) & 1u) << 1) | (((p2h >> (j + 3)) & 1u) << 2));
      *reinterpret_cast<float4*>(orow + 24 + 4 * g) = f;
    }
  }
}

extern "C" void kernel_launch(void* const* d_in, const int* in_sizes, int n_in,
                              void* d_out, int out_size, void* d_ws, size_t ws_size,
                              hipStream_t stream) {
  const float* clusters = (const float*)d_in[0];
  (void)in_sizes; (void)n_in; (void)out_size; (void)d_ws; (void)ws_size;

  // 4 independent wave-tiles per 256-thread block; grid.x*4 = 16 x-tiles.
  dim3 grid(4, NBY, 8);
  fused_dpp<<<grid, 256, 0, stream>>>(clusters, (float*)d_out);
}

// Round 19
// 31.905 us; speedup vs baseline: 1.4737x; 1.0271x over previous
//
#include <hip/hip_runtime.h>

// 3x3 majority, replicate pad, 8 bins, ties -> smallest, 8 fused iterations.
// Bit-sliced planes (3 bits/label). Lane = one FULL tile row of 64 px as a
// u64 (two u32 words). Wave = 64x64 input tile -> 48x48 output (halo 8).
// Vertical: DPP wave_shr1/wave_shl1 bound_ctrl=1 (lanes 0/63 get 0 = halo).
// Horizontal: in-lane u64 funnel shifts. Argmax: bitwise tournament.
// R19 = R18 (asm v_bfi_b32, +10%) plus two codegen fixes:
//  (a) gt4: bfi(d, d&x, g) -> bfi(d, x, g)  [bfi masks with d already]
//      saves 3 VALU x 14 gt4/iter = ~42 ops/iter.
//  (b) DPP batch-hoist: all 32 dpp reads issued in their own loop AFTER the
//      eq-mask blocks -> sources are >=15 insts old, kills the VALU->DPP
//      hazard s_nops (~2 slots per adjacent dpp).

static constexpr int IMG = 768;
static constexpr int NBX = 16;   // 768/48 x-tiles
static constexpr int NBY = 16;   // 768/48 y-tiles

__device__ __forceinline__ unsigned bfi(unsigned m, unsigned a, unsigned b) {
  unsigned r;
  asm("v_bfi_b32 %0, %1, %2, %3" : "=v"(r) : "v"(m), "v"(a), "v"(b));
  return r;   // (a & m) | (b & ~m)
}
__device__ __forceinline__ unsigned dppUp(unsigned x) {   // lane i <- lane i-1
  return (unsigned)__builtin_amdgcn_update_dpp(0, (int)x, 0x138, 0xF, 0xF, true);
}
__device__ __forceinline__ unsigned dppDn(unsigned x) {   // lane i <- lane i+1
  return (unsigned)__builtin_amdgcn_update_dpp(0, (int)x, 0x130, 0xF, 0xF, true);
}
__device__ __forceinline__ unsigned alignb(unsigned hi, unsigned lo, int s) {
  return __builtin_amdgcn_alignbit(hi, lo, s);   // ((hi:lo) >> s) low 32
}

struct C4 { unsigned b0, b1, b2, b3; };

__device__ __forceinline__ unsigned gt4(const C4& x, const C4& y) {  // x > y
  unsigned d = x.b0 ^ y.b0;
  unsigned g = d & x.b0;
  d = x.b1 ^ y.b1; g = bfi(d, x.b1, g);   // (x&d)|(g&~d): level decides if d=1
  d = x.b2 ^ y.b2; g = bfi(d, x.b2, g);
  d = x.b3 ^ y.b3; g = bfi(d, x.b3, g);
  return g;
}
__device__ __forceinline__ C4 sel4(unsigned G, const C4& x, const C4& y) {
  C4 r; r.b0 = bfi(G, x.b0, y.b0); r.b1 = bfi(G, x.b1, y.b1);
  r.b2 = bfi(G, x.b2, y.b2); r.b3 = bfi(G, x.b3, y.b3); return r;
}
__device__ __forceinline__ void tourn8(const C4 c[8],
                                       unsigned& o0, unsigned& o1, unsigned& o2) {
  unsigned g01 = gt4(c[1], c[0]); C4 w01 = sel4(g01, c[1], c[0]);
  unsigned g23 = gt4(c[3], c[2]); C4 w23 = sel4(g23, c[3], c[2]);
  unsigned gA  = gt4(w23, w01);   C4 wA  = sel4(gA, w23, w01);
  unsigned iA0 = bfi(gA, g23, g01), iA1 = gA;
  unsigned g45 = gt4(c[5], c[4]); C4 w45 = sel4(g45, c[5], c[4]);
  unsigned g67 = gt4(c[7], c[6]); C4 w67 = sel4(g67, c[7], c[6]);
  unsigned gB  = gt4(w67, w45);   C4 wB  = sel4(gB, w67, w45);
  unsigned iB0 = bfi(gB, g67, g45), iB1 = gB;
  unsigned gR  = gt4(wB, wA);
  o0 = bfi(gR, iB0, iA0); o1 = bfi(gR, iB1, iA1); o2 = gR;
}

__global__ __launch_bounds__(256, 2) void fused_dpp(
    const float* __restrict__ in, float* __restrict__ out) {
  const int wv = threadIdx.x >> 6;
  const int lane = threadIdx.x & 63;
  const int bx = blockIdx.x * 4 + wv;          // 0..15
  const int by = blockIdx.y, bz = blockIdx.z;

  const float* img = in + (size_t)bz * IMG * IMG;
  const int gyu = by * 48 - 8 + lane;          // unclamped global row

  // ---- stage: one clamped 64-px row -> 6 plane words (branch-free)
  unsigned p0l = 0, p1l = 0, p2l = 0, p0h = 0, p1h = 0, p2h = 0;
  {
    int gy = gyu < 0 ? 0 : (gyu > IMG - 1 ? IMG - 1 : gyu);
    const float* rp = img + (size_t)gy * IMG;
    const int gx0 = bx * 48 - 8;
    const int gxc = gx0 < 0 ? 0 : (gx0 > IMG - 64 ? IMG - 64 : gx0);
#pragma unroll
    for (int g = 0; g < 8; ++g) {
      float4 f = *reinterpret_cast<const float4*>(rp + gxc + 4 * g);
      unsigned u0 = (unsigned)(int)f.x, u1 = (unsigned)(int)f.y;
      unsigned u2 = (unsigned)(int)f.z, u3 = (unsigned)(int)f.w;
      p0l |= ((u0 & 1u) | ((u1 & 1u) << 1) | ((u2 & 1u) << 2) | ((u3 & 1u) << 3)) << (4 * g);
      p1l |= (((u0 >> 1) & 1u) | (((u1 >> 1) & 1u) << 1) | (((u2 >> 1) & 1u) << 2) | (((u3 >> 1) & 1u) << 3)) << (4 * g);
      p2l |= (((u0 >> 2) & 1u) | (((u1 >> 2) & 1u) << 1) | (((u2 >> 2) & 1u) << 2) | (((u3 >> 2) & 1u) << 3)) << (4 * g);
    }
#pragma unroll
    for (int g = 0; g < 8; ++g) {
      float4 f = *reinterpret_cast<const float4*>(rp + gxc + 32 + 4 * g);
      unsigned u0 = (unsigned)(int)f.x, u1 = (unsigned)(int)f.y;
      unsigned u2 = (unsigned)(int)f.z, u3 = (unsigned)(int)f.w;
      p0h |= ((u0 & 1u) | ((u1 & 1u) << 1) | ((u2 & 1u) << 2) | ((u3 & 1u) << 3)) << (4 * g);
      p1h |= (((u0 >> 1) & 1u) | (((u1 >> 1) & 1u) << 1) | (((u2 >> 1) & 1u) << 2) | (((u3 >> 1) & 1u) << 3)) << (4 * g);
      p2h |= (((u0 >> 2) & 1u) | (((u1 >> 2) & 1u) << 1) | (((u2 >> 2) & 1u) << 2) | (((u3 >> 2) & 1u) << 3)) << (4 * g);
    }
    // realign loaded window (px gxc+i) to tile coords (px gx0+j)
    if (bx == 0) {            // desired = loaded << 8 bits (low 8 = halo garbage)
      p0h = alignb(p0h, p0l, 24); p0l <<= 8;
      p1h = alignb(p1h, p1l, 24); p1l <<= 8;
      p2h = alignb(p2h, p2l, 24); p2l <<= 8;
    } else if (bx == NBX - 1) {  // desired = loaded >> 8 bits (top 8 = garbage)
      p0l = alignb(p0h, p0l, 8); p0h >>= 8;
      p1l = alignb(p1h, p1l, 8); p1h >>= 8;
      p2l = alignb(p2h, p2l, 8); p2h >>= 8;
    }
  }

  const bool topE = (by == 0), botE = (by == NBY - 1);
  const bool lxE = (bx == 0), rxE = (bx == NBX - 1);
  const bool pTop = (lane == 8);    // image row 0 (gyu==0) when by==0
  const bool pBot = (lane == 55);   // image row 767 when by==15

#pragma unroll 1
  for (int it = 0; it < 8; ++it) {
    // equality masks per word (15 ops each)
    unsigned e0[8], e1[8];
    {
      unsigned n0 = ~p0l, n1 = ~p1l, n2 = ~p2l;
      unsigned a00 = n1 & n0, a01 = n1 & p0l, a10 = p1l & n0, a11 = p1l & p0l;
      e0[0] = n2 & a00; e0[1] = n2 & a01; e0[2] = n2 & a10; e0[3] = n2 & a11;
      e0[4] = p2l & a00; e0[5] = p2l & a01; e0[6] = p2l & a10; e0[7] = p2l & a11;
    }
    {
      unsigned n0 = ~p0h, n1 = ~p1h, n2 = ~p2h;
      unsigned a00 = n1 & n0, a01 = n1 & p0h, a10 = p1h & n0, a11 = p1h & p0h;
      e1[0] = n2 & a00; e1[1] = n2 & a01; e1[2] = n2 & a10; e1[3] = n2 & a11;
      e1[4] = p2h & a00; e1[5] = p2h & a01; e1[6] = p2h & a10; e1[7] = p2h & a11;
    }

    // batch ALL cross-lane reads (sources >=15 insts old; no hazard nops)
    unsigned euA[8], edA[8], euB[8], edB[8];
#pragma unroll
    for (int b = 0; b < 8; ++b) {
      euA[b] = dppUp(e0[b]); edA[b] = dppDn(e0[b]);
      euB[b] = dppUp(e1[b]); edB[b] = dppDn(e1[b]);
    }

    // vertical 2-bit 3-count per bin per word
    unsigned VL0[8], VH0[8], VL1[8], VH1[8];
#pragma unroll
    for (int b = 0; b < 8; ++b) {
      unsigned eu = euA[b], ed = edA[b];
      if (topE) eu = pTop ? e0[b] : eu;
      if (botE) ed = pBot ? e0[b] : ed;
      unsigned t = eu ^ e0[b];
      VL0[b] = t ^ ed; VH0[b] = bfi(t, ed, e0[b]);   // majority(eu,e,ed)
      eu = euB[b]; ed = edB[b];
      if (topE) eu = pTop ? e1[b] : eu;
      if (botE) ed = pBot ? e1[b] : ed;
      t = eu ^ e1[b];
      VL1[b] = t ^ ed; VH1[b] = bfi(t, ed, e1[b]);
    }

    // horizontal u64 funnel + 2b+2b+2b->4b adder -> per-bin 4-bit counts
    C4 c0[8], c1[8];
#pragma unroll
    for (int b = 0; b < 8; ++b) {
      unsigned AL0 = VL0[b] << 1,               AL1 = alignb(VL1[b], VL0[b], 31);
      unsigned AH0 = VH0[b] << 1,               AH1 = alignb(VH1[b], VH0[b], 31);
      unsigned CL0 = alignb(VL1[b], VL0[b], 1), CL1 = VL1[b] >> 1;
      unsigned CH0 = alignb(VH1[b], VH0[b], 1), CH1 = VH1[b] >> 1;
      if (lxE) { AL0 = bfi(0x100u, VL0[b], AL0); AH0 = bfi(0x100u, VH0[b], AH0); }
      if (rxE) { CL1 = bfi(0x00800000u, VL1[b], CL1); CH1 = bfi(0x00800000u, VH1[b], CH1); }

      // word0 adder: (A + V) + C -> c0[b]
      unsigned s0 = AL0 ^ VL0[b], cc = AL0 & VL0[b];
      unsigned u  = AH0 ^ VH0[b];
      unsigned s1 = u ^ cc, s2 = bfi(u, cc, VH0[b]);
      unsigned t0 = s0 ^ CL0, k0 = s0 & CL0, vv = s1 ^ CH0;
      c0[b].b0 = t0; c0[b].b1 = vv ^ k0;
      unsigned k1 = bfi(vv, k0, CH0);
      c0[b].b2 = s2 ^ k1; c0[b].b3 = s2 & k1;
      // word1 adder -> c1[b]
      s0 = AL1 ^ VL1[b]; cc = AL1 & VL1[b];
      u  = AH1 ^ VH1[b];
      s1 = u ^ cc; s2 = bfi(u, cc, VH1[b]);
      unsigned q0 = s0 ^ CL1; k0 = s0 & CL1; vv = s1 ^ CH1;
      c1[b].b0 = q0; c1[b].b1 = vv ^ k0;
      k1 = bfi(vv, k0, CH1);
      c1[b].b2 = s2 ^ k1; c1[b].b3 = s2 & k1;
    }

    // tournament argmax per word (depth 3; first max = smallest label)
    tourn8(c0, p0l, p1l, p2l);
    tourn8(c1, p0h, p1h, p2h);
  }

  // ---- store: lanes 8..55 = output rows; word0 bits 8..31 -> gx bx*48+0..23,
  // word1 bits 0..23 -> gx bx*48+24..47.
  if (lane >= 8 && lane < 56) {
    float* orow = out + (size_t)bz * IMG * IMG + (size_t)gyu * IMG + bx * 48;
#pragma unroll
    for (int g = 0; g < 6; ++g) {
      const int j = 8 + 4 * g;
      float4 f;
      f.x = (float)(((p0l >> (j + 0)) & 1u) | (((p1l >> (j + 0)) & 1u) << 1) | (((p2l >> (j + 0)) & 1u) << 2));
      f.y = (float)(((p0l >> (j + 1)) & 1u) | (((p1l >> (j + 1)) & 1u) << 1) | (((p2l >> (j + 1)) & 1u) << 2));
      f.z = (float)(((p0l >> (j + 2)) & 1u) | (((p1l >> (j + 2)) & 1u) << 1) | (((p2l >> (j + 2)) & 1u) << 2));
      f.w = (float)(((p0l >> (j + 3)) & 1u) | (((p1l >> (j + 3)) & 1u) << 1) | (((p2l >> (j + 3)) & 1u) << 2));
      *reinterpret_cast<float4*>(orow + 4 * g) = f;
    }
#pragma unroll
    for (int g = 0; g < 6; ++g) {
      const int j = 4 * g;
      float4 f;
      f.x = (float)(((p0h >> (j + 0)) & 1u) | (((p1h >> (j + 0)) & 1u) << 1) | (((p2h >> (j + 0)) & 1u) << 2));
      f.y = (float)(((p0h >> (j + 1)) & 1u) | (((p1h >> (j + 1)) & 1u) << 1) | (((p2h >> (j + 1)) & 1u) << 2));
      f.z = (float)(((p0h >> (j + 2)) & 1u) | (((p1h >> (j + 2)) & 1u) << 1) | (((p2h >> (j + 2)) & 1u) << 2));
      f.w = (float)(((p0h >> (j + 3)) & 1u) | (((p1h >> (j + 3)) & 1u) << 1) | (((p2h >> (j + 3)) & 1u) << 2));
      *reinterpret_cast<float4*>(orow + 24 + 4 * g) = f;
    }
  }
}

extern "C" void kernel_launch(void* const* d_in, const int* in_sizes, int n_in,
                              void* d_out, int out_size, void* d_ws, size_t ws_size,
                              hipStream_t stream) {
  const float* clusters = (const float*)d_in[0];
  (void)in_sizes; (void)n_in; (void)out_size; (void)d_ws; (void)ws_size;

  // 4 independent wave-tiles per 256-thread block; grid.x*4 = 16 x-tiles.
  dim3 grid(4, NBY, 8);
  fused_dpp<<<grid, 256, 0, stream>>>(clusters, (float*)d_out);
}